// Round 6
// baseline (1281.334 us; speedup 1.0000x reference)
//
#include <hip/hip_runtime.h>
#include <stdint.h>

typedef _Float16 f16;
typedef _Float16 f16x8 __attribute__((ext_vector_type(8)));
typedef _Float16 f16x4 __attribute__((ext_vector_type(4)));
typedef float f32x4 __attribute__((ext_vector_type(4)));
typedef int int4v __attribute__((ext_vector_type(4)));
typedef float float4v __attribute__((ext_vector_type(4)));

#define S_LEN 2048
#define D_DIM 64
#define QBLK 64
#define KBLK 64
#define NTHREADS 256
#define KSTEPS 32

// LDS-visibility barrier (sweep 2 only, for Vt dbuf). No vmcnt drain.
#define BARRIER() do { \
    asm volatile("s_waitcnt lgkmcnt(0)" ::: "memory"); \
    __builtin_amdgcn_s_barrier(); \
    asm volatile("" ::: "memory"); \
} while (0)

__device__ __forceinline__ f16x8 cvt8(float4v a, float4v b) {
    f16x8 f;
    f[0]=(f16)a[0]; f[1]=(f16)a[1]; f[2]=(f16)a[2]; f[3]=(f16)a[3];
    f[4]=(f16)b[0]; f[5]=(f16)b[1]; f[6]=(f16)b[2]; f[7]=(f16)b[3];
    return f;
}
__device__ __forceinline__ uint32_t f16b(float x) {
    union { f16 h; uint16_t u; } c; c.h = (f16)x; return c.u;
}

// QK^T for one kstep, K fragments loaded DIRECTLY from global (L2-resident).
// Two ct-halves bound register pressure; loads of a half are all issued
// before any use (single vmcnt wait; mask loads issued later stay untouched).
#define QKT_DIRECT(C, K0) do { \
    _Pragma("unroll") \
    for (int half = 0; half < 2; ++half) { \
        float4v kr[8]; \
        _Pragma("unroll") \
        for (int cc = 0; cc < 2; ++cc) { \
            _Pragma("unroll") \
            for (int h = 0; h < 2; ++h) { \
                const float* kp = kbase + (size_t)((K0) + 16 * (2 * half + cc) + lr) * D_DIM \
                                  + 8 * g + 32 * h; \
                kr[(cc << 2) | (h << 1)]     = *(const float4v*)kp; \
                kr[(cc << 2) | (h << 1) | 1] = *(const float4v*)(kp + 4); \
            } \
        } \
        _Pragma("unroll") \
        for (int cc = 0; cc < 2; ++cc) { \
            const int ct = 2 * half + cc; \
            C[ct] = (f32x4){0.f, 0.f, 0.f, 0.f}; \
            _Pragma("unroll") \
            for (int h = 0; h < 2; ++h) { \
                f16x8 kf = cvt8(kr[(cc << 2) | (h << 1)], kr[(cc << 2) | (h << 1) | 1]); \
                C[ct] = __builtin_amdgcn_mfma_f32_16x16x32_f16(kf, qfrag[h], C[ct], 0, 0, 0); \
            } \
        } \
    } \
} while (0)

// One sweep-1 kstep: barrier-free. MREG = 2-deep mask prefetch register set.
#define S1_BODY(T, MREG) do { \
    const int tt = ((T) + phase) & 31; \
    const int k0 = tt * KBLK; \
    uint32_t bits = 0; \
    _Pragma("unroll") \
    for (int ct = 0; ct < 4; ++ct) { \
        _Pragma("unroll") \
        for (int r = 0; r < 4; ++r) \
            bits |= (MREG[ct][r] != 0 ? 1u : 0u) << (4 * ct + r); \
    } \
    f32x4 c[4]; \
    QKT_DIRECT(c, k0); \
    Mw[tt][tid] = (uint16_t)bits; \
    _Pragma("unroll") \
    for (int ct = 0; ct < 4; ++ct) { \
        _Pragma("unroll") \
        for (int r = 0; r < 4; ++r) { \
            float s = c[ct][r] * 0.125f; \
            float p = ((bits >> (4 * ct + r)) & 1) ? 0.f : __expf(s); /* |s|<=8 */ \
            lacc[r] += p; \
        } \
    } \
    if ((T) + 2 < KSTEPS) {   /* mask prefetch LAST: full kstep in flight before use */ \
        const int tm = ((T) + 2 + phase) & 31; \
        _Pragma("unroll") \
        for (int ct = 0; ct < 4; ++ct) \
            MREG[ct] = __builtin_nontemporal_load( \
                (const int4v*)(mbase + (size_t)tm * KBLK + 16 * ct)); \
    } \
} while (0)

__global__ __launch_bounds__(NTHREADS, 4)
void sdpa_kernel(const float* __restrict__ Qg, const float* __restrict__ Kg,
                 const float* __restrict__ Vg, const int* __restrict__ Mg,
                 float* __restrict__ ProbOut, float* __restrict__ AttnOut)
{
    // LDS: 16 KB (Vt dbuf) + 16 KB (mask bits) = 32 KB -> 4 blocks/CU
    __shared__ f16 Vtlds[2][D_DIM * KBLK];      // [d][k'], k'-permuted, rows XOR-swizzled
    __shared__ uint16_t Mw[KSTEPS][NTHREADS];   // packed mask bits (same-thread RW)

    const int tid  = threadIdx.x;
    const int lane = tid & 63;
    const int wq   = tid >> 6;       // 0..3
    const int g    = lane >> 4;
    const int lr   = lane & 15;

    // XCD-aware swizzle: 256 consecutive logical blocks per XCD (8 heads)
    const int wid = ((blockIdx.x & 7) << 8) | (blockIdx.x >> 3);
    const int bh  = wid >> 5;        // 0..63
    const int qb  = wid & 31;        // 0..31
    // phase-staggered k-ring: de-sync HBM bursts; bh-keyed for L2 K/V locality
    const int phase = ((bh & 3) << 3) | ((qb & 3) << 1);

    const size_t qkv_base = (size_t)bh * S_LEN * D_DIM;
    const size_t mat_base = (size_t)bh * S_LEN * S_LEN;
    const int qw0 = qb * QBLK + wq * 16;

    // ---- Q fragment: lane holds Q[qw0+lr][d = 8g+i+32h] (B-operand layout) ----
    f16x8 qfrag[2];
    {
        const float* qp = Qg + qkv_base + (size_t)(qw0 + lr) * D_DIM + g * 8;
        #pragma unroll
        for (int h = 0; h < 2; ++h)
            qfrag[h] = cvt8(*(const float4v*)(qp + 32 * h),
                            *(const float4v*)(qp + 32 * h + 4));
    }

    // V staging assignment: thread covers k rows {2vrp, 2vrp+1}, d in [vdb, vdb+8)
    const int vrp = tid >> 3;             // 0..31
    const int vdb = (tid & 7) * 8;        // 0..56
    const int vk  = 2 * vrp;
    // V k-permutation: k=16ct+4g+r -> k' = r | ct<<2 | g<<4
    const int vkp = (vk & 3) | (((vk >> 4) & 3) << 2) | (((vk >> 2) & 3) << 4);

    const float* kbase = Kg + qkv_base;
    const float* vbase = Vg + qkv_base;
    const int*   mbase = Mg + mat_base + (size_t)(qw0 + lr) * S_LEN + 4 * g;

    // ================= sweep 1: l = sum(exp(s)) — ZERO barriers =================
    float lacc[4] = {0.f, 0.f, 0.f, 0.f};

    int4v mregA[4], mregB[4];
    {
        const int t1 = (phase + 1) & 31;
        #pragma unroll
        for (int ct = 0; ct < 4; ++ct) {
            mregA[ct] = __builtin_nontemporal_load(
                (const int4v*)(mbase + (size_t)phase * KBLK + 16 * ct));
            mregB[ct] = __builtin_nontemporal_load(
                (const int4v*)(mbase + (size_t)t1 * KBLK + 16 * ct));
        }
    }

    for (int t2 = 0; t2 < KSTEPS; t2 += 2) {
        S1_BODY(t2, mregA);
        S1_BODY(t2 + 1, mregB);
    }

    float lsum = (lacc[0] + lacc[1]) + (lacc[2] + lacc[3]);
    lsum += __shfl_xor(lsum, 16, 64);
    lsum += __shfl_xor(lsum, 32, 64);        // full row sum for q = qw0+lr
    const float inv_l = 1.f / lsum;

    // ================= sweep 2: recompute s, write attn, PV =================
    f32x4 acc[4];
    #pragma unroll
    for (int dt = 0; dt < 4; ++dt) acc[dt] = (f32x4){0.f, 0.f, 0.f, 0.f};

    float4v va0, va1, vb0, vb1;
    {   // prologue: V(phase) -> Vt[0]
        const float* vp = vbase + (size_t)(phase * KBLK + vk) * D_DIM + vdb;
        va0 = *(const float4v*)vp;        va1 = *(const float4v*)(vp + 4);
        vb0 = *(const float4v*)(vp + 64); vb1 = *(const float4v*)(vp + 68);
    }
    #pragma unroll
    for (int j = 0; j < 8; ++j) {
        int d = vdb + j;
        float x0 = j < 4 ? va0[j & 3] : va1[j & 3];
        float x1 = j < 4 ? vb0[j & 3] : vb1[j & 3];
        uint32_t pk = f16b(x0) | (f16b(x1) << 16);
        *(uint32_t*)&Vtlds[0][(d * KBLK + vkp) ^ ((d & 7) << 3)] = pk;
    }

    for (int t = 0; t < KSTEPS; ++t) {
        const int tt  = (t + phase) & 31;
        const int k0  = tt * KBLK;
        const int cur = t & 1;
        BARRIER();   // Vt[cur] visible; writes of Vt[cur^1] gated below

        f32x4 c[4];
        QKT_DIRECT(c, k0);

        if (t + 1 < KSTEPS) {   // V prefetch (L2-resident, lands under attn/PV)
            const int tn = (t + 1 + phase) & 31;
            const float* vp = vbase + (size_t)(tn * KBLK + vk) * D_DIM + vdb;
            va0 = *(const float4v*)vp;        va1 = *(const float4v*)(vp + 4);
            vb0 = *(const float4v*)(vp + 64); vb1 = *(const float4v*)(vp + 68);
        }

        const uint32_t bits = Mw[tt][tid];   // same-thread LDS
        f16x4 pa[4];
        #pragma unroll
        for (int ct = 0; ct < 4; ++ct) {
            float4v av;
            #pragma unroll
            for (int r = 0; r < 4; ++r) {
                float s = c[ct][r] * 0.125f;
                float p = ((bits >> (4 * ct + r)) & 1) ? 0.f : __expf(s);
                float pn = p * inv_l;
                av[r] = pn; pa[ct][r] = (f16)pn;
            }
            __builtin_nontemporal_store(av,
                (float4v*)(AttnOut + mat_base + (size_t)(qw0 + lr) * S_LEN
                           + tt * KBLK + 16 * ct + 4 * g));
        }
        // PV via permuted Vt: per dt, two b128 reads cover all 4 ct
        #pragma unroll
        for (int dt = 0; dt < 4; ++dt) {
            int row = 16 * dt + lr;
            f16x8 vfA = *(const f16x8*)&Vtlds[cur][(row * KBLK + 16 * g)     ^ ((lr & 7) << 3)];
            f16x8 vfB = *(const f16x8*)&Vtlds[cur][(row * KBLK + 16 * g + 8) ^ ((lr & 7) << 3)];
            acc[dt] = __builtin_amdgcn_mfma_f32_16x16x16f16(
                pa[0], __builtin_shufflevector(vfA, vfA, 0, 1, 2, 3), acc[dt], 0, 0, 0);
            acc[dt] = __builtin_amdgcn_mfma_f32_16x16x16f16(
                pa[1], __builtin_shufflevector(vfA, vfA, 4, 5, 6, 7), acc[dt], 0, 0, 0);
            acc[dt] = __builtin_amdgcn_mfma_f32_16x16x16f16(
                pa[2], __builtin_shufflevector(vfB, vfB, 0, 1, 2, 3), acc[dt], 0, 0, 0);
            acc[dt] = __builtin_amdgcn_mfma_f32_16x16x16f16(
                pa[3], __builtin_shufflevector(vfB, vfB, 4, 5, 6, 7), acc[dt], 0, 0, 0);
        }
        if (t + 1 < KSTEPS) {   // stage next Vt (ds_write waits V loads via vmcnt)
            #pragma unroll
            for (int j = 0; j < 8; ++j) {
                int d = vdb + j;
                float x0 = j < 4 ? va0[j & 3] : va1[j & 3];
                float x1 = j < 4 ? vb0[j & 3] : vb1[j & 3];
                uint32_t pk = f16b(x0) | (f16b(x1) << 16);
                *(uint32_t*)&Vtlds[cur ^ 1][(d * KBLK + vkp) ^ ((d & 7) << 3)] = pk;
            }
        }
    }

    // epilogue: prob (already normalized; C/D layout col=lr, row=4g+r)
    #pragma unroll
    for (int dt = 0; dt < 4; ++dt) {
        #pragma unroll
        for (int r = 0; r < 4; ++r) {
            int qrow = qw0 + 4 * g + r;
            ProbOut[qkv_base + (size_t)qrow * D_DIM + 16 * dt + lr] = acc[dt][r];
        }
    }
}

extern "C" void kernel_launch(void* const* d_in, const int* in_sizes, int n_in,
                              void* d_out, int out_size, void* d_ws, size_t ws_size,
                              hipStream_t stream)
{
    const float* Q = (const float*)d_in[0];
    const float* K = (const float*)d_in[1];
    const float* V = (const float*)d_in[2];
    const int*   M = (const int*)d_in[3];

    float* prob = (float*)d_out;                          // [4,16,2048,64]
    float* attn = prob + (size_t)4 * 16 * 2048 * 64;      // [4,16,2048,2048]

    dim3 grid(64 * (S_LEN / QBLK));   // 2048
    dim3 block(NTHREADS);
    sdpa_kernel<<<grid, block, 0, stream>>>(Q, K, V, M, prob, attn);
}

// Round 7
// 878.548 us; speedup vs baseline: 1.4585x; 1.4585x over previous
//
#include <hip/hip_runtime.h>
#include <stdint.h>

typedef _Float16 f16;
typedef _Float16 f16x8 __attribute__((ext_vector_type(8)));
typedef _Float16 f16x4 __attribute__((ext_vector_type(4)));
typedef float f32x4 __attribute__((ext_vector_type(4)));
typedef int int4v __attribute__((ext_vector_type(4)));
typedef float float4v __attribute__((ext_vector_type(4)));

#define S_LEN 2048
#define D_DIM 64
#define QBLK 64
#define KBLK 64
#define NTHREADS 256
#define KSTEPS 32
#define NBLOCKS (64 * (S_LEN / QBLK))   // 2048

// LDS-visibility barrier: no vmcnt drain — global loads/stores stay in flight (T4).
#define BARRIER() do { \
    asm volatile("s_waitcnt lgkmcnt(0)" ::: "memory"); \
    __builtin_amdgcn_s_barrier(); \
    asm volatile("" ::: "memory"); \
} while (0)

__device__ __forceinline__ f16x8 cvt8(float4v a, float4v b) {
    f16x8 f;
    f[0]=(f16)a[0]; f[1]=(f16)a[1]; f[2]=(f16)a[2]; f[3]=(f16)a[3];
    f[4]=(f16)b[0]; f[5]=(f16)b[1]; f[6]=(f16)b[2]; f[7]=(f16)b[3];
    return f;
}
__device__ __forceinline__ uint32_t f16b(float x) {
    union { f16 h; uint16_t u; } c; c.h = (f16)x; return c.u;
}

// ===================== kernel 1: l = sum(exp(s)), pack mask bits =====================
// Bits aliases the prob region of d_out (exact fit: 2048 blk * 256 thr * 32 u16 = 33.55 MB).
// l stored at attn[row][2047] (k2 reads it in its prologue before any attn writes).
__global__ __launch_bounds__(NTHREADS, 4)
void sdpa_sum(const float* __restrict__ Qg, const float* __restrict__ Kg,
              const int* __restrict__ Mg, float* __restrict__ AttnOut,
              uint16_t* __restrict__ Bits)
{
    __shared__ f16 Klds[2][KBLK * D_DIM];   // 16 KB dbuf, rows XOR-swizzled

    const int tid  = threadIdx.x;
    const int lane = tid & 63;
    const int wq   = tid >> 6;       // 0..3
    const int g    = lane >> 4;
    const int lr   = lane & 15;

    const int wid = ((blockIdx.x & 7) << 8) | (blockIdx.x >> 3);   // XCD swizzle
    const int bh  = wid >> 5;
    const int qb  = wid & 31;
    const int phase = ((bh & 3) << 3) | ((qb & 3) << 1);

    const size_t qkv_base = (size_t)bh * S_LEN * D_DIM;
    const size_t mat_base = (size_t)bh * S_LEN * S_LEN;
    const int qw0 = qb * QBLK + wq * 16;

    f16x8 qfrag[2];
    {
        const float* qp = Qg + qkv_base + (size_t)(qw0 + lr) * D_DIM + g * 8;
        #pragma unroll
        for (int h = 0; h < 2; ++h)
            qfrag[h] = cvt8(*(const float4v*)(qp + 32 * h),
                            *(const float4v*)(qp + 32 * h + 4));
    }

    // K staging: thread covers row srow, 16 floats at scol
    const int srow  = tid >> 2;
    const int scol  = (tid & 3) * 16;
    const int sidx0 = (srow * D_DIM + scol)     ^ ((srow & 7) << 3);
    const int sidx1 = (srow * D_DIM + scol + 8) ^ ((srow & 7) << 3);

    const float* kbase = Kg + qkv_base;
    const int*   mbase = Mg + mat_base + (size_t)(qw0 + lr) * S_LEN + 4 * g;

    float lacc[4] = {0.f, 0.f, 0.f, 0.f};

    float4v kra, krb, krc, krd;
    int4v mreg[4];
    {   // prologue: K(phase) + mask(phase)
        const float* kp = kbase + (size_t)(phase * KBLK + srow) * D_DIM + scol;
        kra = *(const float4v*)kp;       krb = *(const float4v*)(kp + 4);
        krc = *(const float4v*)(kp + 8); krd = *(const float4v*)(kp + 12);
        #pragma unroll
        for (int ct = 0; ct < 4; ++ct)
            mreg[ct] = __builtin_nontemporal_load(
                (const int4v*)(mbase + (size_t)phase * KBLK + 16 * ct));
    }
    *(f16x8*)&Klds[0][sidx0] = cvt8(kra, krb);
    *(f16x8*)&Klds[0][sidx1] = cvt8(krc, krd);

    for (int t = 0; t < KSTEPS; ++t) {
        const int tt  = (t + phase) & 31;
        const int cur = t & 1;
        BARRIER();
        uint32_t bits = 0;
        #pragma unroll
        for (int ct = 0; ct < 4; ++ct) {
            #pragma unroll
            for (int r = 0; r < 4; ++r)
                bits |= (mreg[ct][r] != 0 ? 1u : 0u) << (4 * ct + r);
        }
        if (t + 1 < KSTEPS) {   // K first (ds_write's vmcnt wait leaves mask in flight)
            const int tn = (t + 1 + phase) & 31;
            const float* kp = kbase + (size_t)(tn * KBLK + srow) * D_DIM + scol;
            kra = *(const float4v*)kp;       krb = *(const float4v*)(kp + 4);
            krc = *(const float4v*)(kp + 8); krd = *(const float4v*)(kp + 12);
            #pragma unroll
            for (int ct = 0; ct < 4; ++ct)
                mreg[ct] = __builtin_nontemporal_load(
                    (const int4v*)(mbase + (size_t)tn * KBLK + 16 * ct));
        }
        f32x4 c[4];
        #pragma unroll
        for (int ct = 0; ct < 4; ++ct) {
            c[ct] = (f32x4){0.f, 0.f, 0.f, 0.f};
            #pragma unroll
            for (int h = 0; h < 2; ++h) {
                int rowl = 16 * ct + lr;
                int idx = (rowl * D_DIM + 8 * g + 32 * h) ^ ((rowl & 7) << 3);
                f16x8 kf = *(const f16x8*)(&Klds[cur][idx]);
                c[ct] = __builtin_amdgcn_mfma_f32_16x16x32_f16(kf, qfrag[h], c[ct], 0, 0, 0);
            }
        }
        Bits[((size_t)wid * 32 + tt) * NTHREADS + tid] = (uint16_t)bits;
        #pragma unroll
        for (int ct = 0; ct < 4; ++ct) {
            #pragma unroll
            for (int r = 0; r < 4; ++r) {
                float s = c[ct][r] * 0.125f;
                float p = ((bits >> (4 * ct + r)) & 1) ? 0.f : __expf(s);   // |s|<=8
                lacc[r] += p;
            }
        }
        if (t + 1 < KSTEPS) {
            *(f16x8*)&Klds[cur ^ 1][sidx0] = cvt8(kra, krb);
            *(f16x8*)&Klds[cur ^ 1][sidx1] = cvt8(krc, krd);
        }
    }

    float lsum = (lacc[0] + lacc[1]) + (lacc[2] + lacc[3]);
    lsum += __shfl_xor(lsum, 16, 64);
    lsum += __shfl_xor(lsum, 32, 64);
    if (g == 0)   // one lane per q-row stores l at attn[row][2047]
        AttnOut[mat_base + (size_t)(qw0 + lr) * S_LEN + (S_LEN - 1)] = lsum;
}

// ===================== kernel 2: recompute s, write attn, PV =====================
__global__ __launch_bounds__(NTHREADS, 4)
void sdpa_av(const float* __restrict__ Qg, const float* __restrict__ Kg,
             const float* __restrict__ Vg, const uint16_t* __restrict__ Bits,
             float* __restrict__ ProbOut, float* __restrict__ AttnOut)
{
    __shared__ f16 Klds[2][KBLK * D_DIM];    // 16 KB
    __shared__ f16 Vtlds[2][D_DIM * KBLK];   // 16 KB, [d][k'] permuted

    const int tid  = threadIdx.x;
    const int lane = tid & 63;
    const int wq   = tid >> 6;
    const int g    = lane >> 4;
    const int lr   = lane & 15;

    const int wid = ((blockIdx.x & 7) << 8) | (blockIdx.x >> 3);
    const int bh  = wid >> 5;
    const int qb  = wid & 31;
    const int phase = ((bh & 3) << 3) | ((qb & 3) << 1);

    const size_t qkv_base = (size_t)bh * S_LEN * D_DIM;
    const size_t mat_base = (size_t)bh * S_LEN * S_LEN;
    const int qw0 = qb * QBLK + wq * 16;

    f16x8 qfrag[2];
    {
        const float* qp = Qg + qkv_base + (size_t)(qw0 + lr) * D_DIM + g * 8;
        #pragma unroll
        for (int h = 0; h < 2; ++h)
            qfrag[h] = cvt8(*(const float4v*)(qp + 32 * h),
                            *(const float4v*)(qp + 32 * h + 4));
    }

    // l (written by k1 at attn[row][2047]) — read BEFORE any attn writes
    const float inv_l = 1.f /
        AttnOut[mat_base + (size_t)(qw0 + lr) * S_LEN + (S_LEN - 1)];

    const int srow  = tid >> 2;
    const int scol  = (tid & 3) * 16;
    const int sidx0 = (srow * D_DIM + scol)     ^ ((srow & 7) << 3);
    const int sidx1 = (srow * D_DIM + scol + 8) ^ ((srow & 7) << 3);
    const int vrp = tid >> 3;             // row pair 2vrp, 2vrp+1
    const int vdb = (tid & 7) * 8;        // d base
    const int vk  = 2 * vrp;
    const int vkp = (vk & 3) | (((vk >> 4) & 3) << 2) | (((vk >> 2) & 3) << 4);

    const float* kbase = Kg + qkv_base;
    const float* vbase = Vg + qkv_base;
    const uint16_t* bbase = Bits + (size_t)wid * 32 * NTHREADS + tid;

    f32x4 acc[4];
    #pragma unroll
    for (int dt = 0; dt < 4; ++dt) acc[dt] = (f32x4){0.f, 0.f, 0.f, 0.f};

    float4v kra, krb, krc, krd, va0, va1, vb0, vb1;
    uint32_t breg;
    {   // prologue: K(phase), V(phase), bits(phase)
        const float* kp = kbase + (size_t)(phase * KBLK + srow) * D_DIM + scol;
        kra = *(const float4v*)kp;       krb = *(const float4v*)(kp + 4);
        krc = *(const float4v*)(kp + 8); krd = *(const float4v*)(kp + 12);
        const float* vp = vbase + (size_t)(phase * KBLK + vk) * D_DIM + vdb;
        va0 = *(const float4v*)vp;            va1 = *(const float4v*)(vp + 4);
        vb0 = *(const float4v*)(vp + D_DIM);  vb1 = *(const float4v*)(vp + D_DIM + 4);
        breg = bbase[(size_t)phase * NTHREADS];
    }
    *(f16x8*)&Klds[0][sidx0] = cvt8(kra, krb);
    *(f16x8*)&Klds[0][sidx1] = cvt8(krc, krd);
    #pragma unroll
    for (int j = 0; j < 8; ++j) {
        int d = vdb + j;
        float x0 = j < 4 ? va0[j & 3] : va1[j & 3];
        float x1 = j < 4 ? vb0[j & 3] : vb1[j & 3];
        *(uint32_t*)&Vtlds[0][(d * KBLK + vkp) ^ ((d & 7) << 3)] =
            f16b(x0) | (f16b(x1) << 16);
    }

    for (int t = 0; t < KSTEPS; ++t) {
        const int tt  = (t + phase) & 31;
        const int cur = t & 1;
        BARRIER();
        if (t + 1 < KSTEPS) {
            const int tn = (t + 1 + phase) & 31;
            const float* kp = kbase + (size_t)(tn * KBLK + srow) * D_DIM + scol;
            kra = *(const float4v*)kp;       krb = *(const float4v*)(kp + 4);
            krc = *(const float4v*)(kp + 8); krd = *(const float4v*)(kp + 12);
            const float* vp = vbase + (size_t)(tn * KBLK + vk) * D_DIM + vdb;
            va0 = *(const float4v*)vp;            va1 = *(const float4v*)(vp + 4);
            vb0 = *(const float4v*)(vp + D_DIM);  vb1 = *(const float4v*)(vp + D_DIM + 4);
        }
        f32x4 c[4];
        #pragma unroll
        for (int ct = 0; ct < 4; ++ct) {
            c[ct] = (f32x4){0.f, 0.f, 0.f, 0.f};
            #pragma unroll
            for (int h = 0; h < 2; ++h) {
                int rowl = 16 * ct + lr;
                int idx = (rowl * D_DIM + 8 * g + 32 * h) ^ ((rowl & 7) << 3);
                f16x8 kf = *(const f16x8*)(&Klds[cur][idx]);
                c[ct] = __builtin_amdgcn_mfma_f32_16x16x32_f16(kf, qfrag[h], c[ct], 0, 0, 0);
            }
        }
        const uint32_t bits = breg;
        if (t + 1 < KSTEPS)
            breg = bbase[(size_t)((t + 1 + phase) & 31) * NTHREADS];

        f16x4 pa[4];
        #pragma unroll
        for (int ct = 0; ct < 4; ++ct) {
            float4v av;
            #pragma unroll
            for (int r = 0; r < 4; ++r) {
                float s = c[ct][r] * 0.125f;
                float p = ((bits >> (4 * ct + r)) & 1) ? 0.f : __expf(s);
                float pn = p * inv_l;
                av[r] = pn; pa[ct][r] = (f16)pn;
            }
            // plain store (no nt): let L2 write-combine full lines
            *(float4v*)(AttnOut + mat_base + (size_t)(qw0 + lr) * S_LEN
                        + tt * KBLK + 16 * ct + 4 * g) = av;
        }
        #pragma unroll
        for (int dt = 0; dt < 4; ++dt) {
            int row = 16 * dt + lr;
            f16x8 vfA = *(const f16x8*)&Vtlds[cur][(row * KBLK + 16 * g)     ^ ((lr & 7) << 3)];
            f16x8 vfB = *(const f16x8*)&Vtlds[cur][(row * KBLK + 16 * g + 8) ^ ((lr & 7) << 3)];
            acc[dt] = __builtin_amdgcn_mfma_f32_16x16x16f16(
                pa[0], __builtin_shufflevector(vfA, vfA, 0, 1, 2, 3), acc[dt], 0, 0, 0);
            acc[dt] = __builtin_amdgcn_mfma_f32_16x16x16f16(
                pa[1], __builtin_shufflevector(vfA, vfA, 4, 5, 6, 7), acc[dt], 0, 0, 0);
            acc[dt] = __builtin_amdgcn_mfma_f32_16x16x16f16(
                pa[2], __builtin_shufflevector(vfB, vfB, 0, 1, 2, 3), acc[dt], 0, 0, 0);
            acc[dt] = __builtin_amdgcn_mfma_f32_16x16x16f16(
                pa[3], __builtin_shufflevector(vfB, vfB, 4, 5, 6, 7), acc[dt], 0, 0, 0);
        }
        if (t + 1 < KSTEPS) {
            *(f16x8*)&Klds[cur ^ 1][sidx0] = cvt8(kra, krb);
            *(f16x8*)&Klds[cur ^ 1][sidx1] = cvt8(krc, krd);
            #pragma unroll
            for (int j = 0; j < 8; ++j) {
                int d = vdb + j;
                float x0 = j < 4 ? va0[j & 3] : va1[j & 3];
                float x1 = j < 4 ? vb0[j & 3] : vb1[j & 3];
                *(uint32_t*)&Vtlds[cur ^ 1][(d * KBLK + vkp) ^ ((d & 7) << 3)] =
                    f16b(x0) | (f16b(x1) << 16);
            }
        }
    }

    // epilogue: prob (overwrites the Bits region — all bits already consumed)
    #pragma unroll
    for (int dt = 0; dt < 4; ++dt) {
        #pragma unroll
        for (int r = 0; r < 4; ++r) {
            int qrow = qw0 + 4 * g + r;
            ProbOut[qkv_base + (size_t)qrow * D_DIM + 16 * dt + lr] = acc[dt][r];
        }
    }
}

extern "C" void kernel_launch(void* const* d_in, const int* in_sizes, int n_in,
                              void* d_out, int out_size, void* d_ws, size_t ws_size,
                              hipStream_t stream)
{
    const float* Q = (const float*)d_in[0];
    const float* K = (const float*)d_in[1];
    const float* V = (const float*)d_in[2];
    const int*   M = (const int*)d_in[3];

    float* prob = (float*)d_out;                          // [4,16,2048,64]
    float* attn = prob + (size_t)4 * 16 * 2048 * 64;      // [4,16,2048,2048]
    uint16_t* bits = (uint16_t*)prob;                     // aliases prob (exact fit)

    dim3 grid(NBLOCKS), block(NTHREADS);
    sdpa_sum<<<grid, block, 0, stream>>>(Q, K, M, attn, bits);
    sdpa_av <<<grid, block, 0, stream>>>(Q, K, V, bits, prob, attn);
}

// Round 8
// 637.519 us; speedup vs baseline: 2.0099x; 1.3781x over previous
//
#include <hip/hip_runtime.h>
#include <stdint.h>

typedef _Float16 f16;
typedef _Float16 f16x8 __attribute__((ext_vector_type(8)));
typedef _Float16 f16x4 __attribute__((ext_vector_type(4)));
typedef float f32x4 __attribute__((ext_vector_type(4)));
typedef int int2v __attribute__((ext_vector_type(2)));
typedef float float4v __attribute__((ext_vector_type(4)));

#define S_LEN 2048
#define D_DIM 64
#define QBLK 128
#define KBLK 64
#define NTHREADS 512
#define KSTEPS 32

// LDS-visibility barrier: no vmcnt drain (T4) — global loads/stores stay in flight.
#define BARRIER() do { \
    asm volatile("s_waitcnt lgkmcnt(0)" ::: "memory"); \
    __builtin_amdgcn_s_barrier(); \
    asm volatile("" ::: "memory"); \
} while (0)

__device__ __forceinline__ f16x8 cvt8(float4v a, float4v b) {
    f16x8 f;
    f[0]=(f16)a[0]; f[1]=(f16)a[1]; f[2]=(f16)a[2]; f[3]=(f16)a[3];
    f[4]=(f16)b[0]; f[5]=(f16)b[1]; f[6]=(f16)b[2]; f[7]=(f16)b[3];
    return f;
}
__device__ __forceinline__ uint32_t f16b(float x) {
    union { f16 h; uint16_t u; } c; c.h = (f16)x; return c.u;
}

// QK^T from swizzled Klds[CUR]: c[ct][r] = S[q=qw0+lr][k = tile*64 + 16ct + 4g + r]
#define QKT_LDS(C, CUR) do { \
    _Pragma("unroll") \
    for (int ct = 0; ct < 4; ++ct) { \
        C[ct] = (f32x4){0.f, 0.f, 0.f, 0.f}; \
        _Pragma("unroll") \
        for (int h = 0; h < 2; ++h) { \
            int rowl = 16 * ct + lr; \
            int idx = (rowl * D_DIM + 8 * g + 32 * h) ^ ((rowl & 7) << 3); \
            f16x8 kf = *(const f16x8*)(&Klds[CUR][idx]); \
            C[ct] = __builtin_amdgcn_mfma_f32_16x16x32_f16(kf, qfrag[h], C[ct], 0, 0, 0); \
        } \
    } \
} while (0)

// bits u32 for group G live in the block's final-pair attn region (same-thread RW)
#define BITSADDR(G) ((uint32_t*)(AttnOut + mat_base + \
    (size_t)(qb * QBLK + 4 * (G) + (tid >> 7)) * S_LEN + ttl + (tid & 127)))

__global__ __launch_bounds__(NTHREADS, 4)
void sdpa_kernel(const float* __restrict__ Qg, const float* __restrict__ Kg,
                 const float* __restrict__ Vg, const int* __restrict__ Mg,
                 float* __restrict__ ProbOut, float* __restrict__ AttnOut)
{
    // LDS: 16 (K dbuf) + 16 (Vt dbuf) + 32 (attn stage) = 64 KB -> 2 blocks/CU
    __shared__ f16 Klds[2][KBLK * D_DIM];     // [k][d], rows XOR-swizzled
    __shared__ f16 Vtlds[2][D_DIM * KBLK];    // [d][k'], k'-permuted, rows XOR-swizzled
    __shared__ f16 Astage[8][16 * 128];       // per-wave attn f16 tile [q16][col128], swizzled

    const int tid  = threadIdx.x;
    const int lane = tid & 63;
    const int wq   = tid >> 6;
    const int g    = lane >> 4;
    const int lr   = lane & 15;

    const int wid = ((blockIdx.x & 7) << 7) + (blockIdx.x >> 3);   // XCD swizzle
    const int bh  = wid >> 4;
    const int qb  = wid & 15;
    const int phase = ((bh & 3) << 3) | ((qb & 3) << 1);           // even -> group-aligned

    const size_t qkv_base = (size_t)bh * S_LEN * D_DIM;
    const size_t mat_base = (size_t)bh * S_LEN * S_LEN;
    const int qw0 = qb * QBLK + wq * 16;
    const int ttl = ((30 + phase) & 31) * KBLK;   // final pair's col base (bits region)

    // ---- Q fragment: lane holds Q[qw0+lr][d = 8g+i+32h] (B-operand layout) ----
    f16x8 qfrag[2];
    {
        const float* qp = Qg + qkv_base + (size_t)(qw0 + lr) * D_DIM + g * 8;
        #pragma unroll
        for (int h = 0; h < 2; ++h)
            qfrag[h] = cvt8(*(const float4v*)(qp + 32 * h),
                            *(const float4v*)(qp + 32 * h + 4));
    }

    const int srow = tid >> 3, scol = (tid & 7) * 8;
    const int sidx = (srow * D_DIM + scol) ^ ((srow & 7) << 3);
    const int vrp  = tid >> 4, vdb = (tid & 15) * 4;
    const int vk   = 2 * vrp;
    const int vkp  = (vk & 3) | (((vk >> 4) & 3) << 2) | (((vk >> 2) & 3) << 4);

    const float* kbase = Kg + qkv_base;
    const float* vbase = Vg + qkv_base;

    // ============ sweep 1: l = sum(exp(s)); bits -> attn-region scratch ============
    float lacc[4] = {0.f, 0.f, 0.f, 0.f};
    float4v ka, kb;
    int2v mr[16];
    uint32_t bitsCur = 0;

    {   // prologue: K(phase) -> Klds[0]; mask group 0 (16 contiguous 512B row reads)
        const float* kp = kbase + (size_t)(phase * KBLK + srow) * D_DIM + scol;
        ka = *(const float4v*)kp; kb = *(const float4v*)(kp + 4);
        #pragma unroll
        for (int i = 0; i < 16; ++i)
            mr[i] = __builtin_nontemporal_load(
                (const int2v*)(Mg + mat_base + (size_t)(qw0 + i) * S_LEN
                               + phase * KBLK + 2 * lane));
        *(f16x8*)&Klds[0][sidx] = cvt8(ka, kb);
    }

#define S1E(T) do { \
    BARRIER(); \
    /* pack 2-bit nibbles: lane l holds mask(row i, cols c0+2l,c0+2l+1) for i=0..15 */ \
    uint32_t nib = 0; \
    _Pragma("unroll") \
    for (int i = 0; i < 16; ++i) \
        nib |= ((mr[i][0] != 0 ? 1u : 0u) | (mr[i][1] != 0 ? 2u : 0u)) << (2 * i); \
    /* redistribute: bits[4ct+r] of kstep j from lane 32j+8ct+2g+(r>>1), bit r&1 */ \
    uint32_t bits0 = 0, bits1 = 0; \
    _Pragma("unroll") \
    for (int ct = 0; ct < 4; ++ct) { \
        _Pragma("unroll") \
        for (int rp = 0; rp < 2; ++rp) { \
            int s0 = 8 * ct + 2 * g + rp; \
            uint32_t n0 = (uint32_t)__shfl((int)nib, s0, 64); \
            uint32_t n1 = (uint32_t)__shfl((int)nib, s0 + 32, 64); \
            bits0 |= ((n0 >> (2 * lr)) & 3u) << (4 * ct + 2 * rp); \
            bits1 |= ((n1 >> (2 * lr)) & 3u) << (4 * ct + 2 * rp); \
        } \
    } \
    bitsCur = bits0 | (bits1 << 16); \
    *BITSADDR((T) >> 1) = bitsCur; \
    if ((T) + 1 < KSTEPS) { \
        const int tn = ((T) + 1 + phase) & 31; \
        const float* kp = kbase + (size_t)(tn * KBLK + srow) * D_DIM + scol; \
        ka = *(const float4v*)kp; kb = *(const float4v*)(kp + 4); \
    } \
    f32x4 c[4]; \
    QKT_LDS(c, (T) & 1); \
    _Pragma("unroll") \
    for (int ct = 0; ct < 4; ++ct) { \
        _Pragma("unroll") \
        for (int r = 0; r < 4; ++r) { \
            float s = c[ct][r] * 0.125f; \
            float p = ((bitsCur >> (4 * ct + r)) & 1) ? 0.f : __expf(s); /* |s|<=8 */ \
            lacc[r] += p; \
        } \
    } \
    if ((T) + 1 < KSTEPS) *(f16x8*)&Klds[((T) & 1) ^ 1][sidx] = cvt8(ka, kb); \
} while (0)

#define S1O(T) do { \
    BARRIER(); \
    if ((T) + 1 < KSTEPS) { \
        const int tn = ((T) + 1 + phase) & 31; \
        const float* kp = kbase + (size_t)(tn * KBLK + srow) * D_DIM + scol; \
        ka = *(const float4v*)kp; kb = *(const float4v*)(kp + 4); \
        _Pragma("unroll") \
        for (int i = 0; i < 16; ++i)   /* next group's mask: 16 x 512B contiguous */ \
            mr[i] = __builtin_nontemporal_load( \
                (const int2v*)(Mg + mat_base + (size_t)(qw0 + i) * S_LEN \
                               + tn * KBLK + 2 * lane)); \
    } \
    f32x4 c[4]; \
    QKT_LDS(c, (T) & 1); \
    { uint32_t b1 = bitsCur >> 16; \
      _Pragma("unroll") \
      for (int ct = 0; ct < 4; ++ct) { \
          _Pragma("unroll") \
          for (int r = 0; r < 4; ++r) { \
              float s = c[ct][r] * 0.125f; \
              float p = ((b1 >> (4 * ct + r)) & 1) ? 0.f : __expf(s); \
              lacc[r] += p; \
          } \
      } } \
    if ((T) + 1 < KSTEPS) *(f16x8*)&Klds[((T) & 1) ^ 1][sidx] = cvt8(ka, kb); \
} while (0)

    S1E(0);  S1O(1);  S1E(2);  S1O(3);  S1E(4);  S1O(5);  S1E(6);  S1O(7);
    S1E(8);  S1O(9);  S1E(10); S1O(11); S1E(12); S1O(13); S1E(14); S1O(15);
    S1E(16); S1O(17); S1E(18); S1O(19); S1E(20); S1O(21); S1E(22); S1O(23);
    S1E(24); S1O(25); S1E(26); S1O(27); S1E(28); S1O(29); S1E(30); S1O(31);

    float lsum = (lacc[0] + lacc[1]) + (lacc[2] + lacc[3]);
    lsum += __shfl_xor(lsum, 16, 64);
    lsum += __shfl_xor(lsum, 32, 64);
    const float inv_l = 1.f / lsum;

    // boundary: drain bits stores (orders them before sweep-2's final attn stores)
    asm volatile("s_waitcnt vmcnt(0)" ::: "memory");
    __syncthreads();

    // ============ sweep 2: recompute s, stage+store attn, PV ============
    f32x4 acc[4];
    #pragma unroll
    for (int dt = 0; dt < 4; ++dt) acc[dt] = (f32x4){0.f, 0.f, 0.f, 0.f};

    float4v va, vb;
    uint32_t buCur, buNxt = 0;
    {   // prologue: K(phase)->Klds[0], V(phase)->Vt[0], bits(group 0)
        const float* kp = kbase + (size_t)(phase * KBLK + srow) * D_DIM + scol;
        ka = *(const float4v*)kp; kb = *(const float4v*)(kp + 4);
        const float* vp = vbase + (size_t)(phase * KBLK + vk) * D_DIM + vdb;
        va = *(const float4v*)vp; vb = *(const float4v*)(vp + D_DIM);
        buCur = *BITSADDR(0);
        *(f16x8*)&Klds[0][sidx] = cvt8(ka, kb);
        #pragma unroll
        for (int j = 0; j < 4; ++j) {
            int d = vdb + j;
            *(uint32_t*)&Vtlds[0][(d * KBLK + vkp) ^ ((d & 7) << 3)] =
                f16b(va[j]) | (f16b(vb[j]) << 16);
        }
    }

#define S2_CORE(T, BITS, PAR) do { \
    f32x4 c[4]; \
    QKT_LDS(c, (T) & 1); \
    f16x4 pa[4]; \
    _Pragma("unroll") \
    for (int ct = 0; ct < 4; ++ct) { \
        float av[4]; \
        _Pragma("unroll") \
        for (int r = 0; r < 4; ++r) { \
            float s = c[ct][r] * 0.125f; \
            float p = ((BITS) >> (4 * ct + r) & 1) ? 0.f : __expf(s); \
            av[r] = p * inv_l; pa[ct][r] = (f16)av[r]; \
        } \
        _Pragma("unroll") \
        for (int u = 0; u < 2; ++u) { \
            int col = 64 * (PAR) + 16 * ct + 4 * g + 2 * u; \
            int idx = (lr * 128 + col) ^ ((lr & 7) << 3); \
            *(uint32_t*)&Astage[wq][idx] = f16b(av[2 * u]) | (f16b(av[2 * u + 1]) << 16); \
        } \
    } \
    _Pragma("unroll") \
    for (int dt = 0; dt < 4; ++dt) { \
        int row = 16 * dt + lr; \
        f16x8 vfA = *(const f16x8*)&Vtlds[(T) & 1][(row * KBLK + 16 * g)     ^ ((lr & 7) << 3)]; \
        f16x8 vfB = *(const f16x8*)&Vtlds[(T) & 1][(row * KBLK + 16 * g + 8) ^ ((lr & 7) << 3)]; \
        acc[dt] = __builtin_amdgcn_mfma_f32_16x16x16f16( \
            pa[0], __builtin_shufflevector(vfA, vfA, 0, 1, 2, 3), acc[dt], 0, 0, 0); \
        acc[dt] = __builtin_amdgcn_mfma_f32_16x16x16f16( \
            pa[1], __builtin_shufflevector(vfA, vfA, 4, 5, 6, 7), acc[dt], 0, 0, 0); \
        acc[dt] = __builtin_amdgcn_mfma_f32_16x16x16f16( \
            pa[2], __builtin_shufflevector(vfB, vfB, 0, 1, 2, 3), acc[dt], 0, 0, 0); \
        acc[dt] = __builtin_amdgcn_mfma_f32_16x16x16f16( \
            pa[3], __builtin_shufflevector(vfB, vfB, 4, 5, 6, 7), acc[dt], 0, 0, 0); \
    } \
} while (0)

#define S2_LOADS(T) do { \
    if ((T) + 1 < KSTEPS) { \
        const int tn = ((T) + 1 + phase) & 31; \
        const float* kp = kbase + (size_t)(tn * KBLK + srow) * D_DIM + scol; \
        ka = *(const float4v*)kp; kb = *(const float4v*)(kp + 4); \
        const float* vp = vbase + (size_t)(tn * KBLK + vk) * D_DIM + vdb; \
        va = *(const float4v*)vp; vb = *(const float4v*)(vp + D_DIM); \
    } \
} while (0)

#define S2_STAGE(T) do { \
    if ((T) + 1 < KSTEPS) { \
        *(f16x8*)&Klds[((T) & 1) ^ 1][sidx] = cvt8(ka, kb); \
        _Pragma("unroll") \
        for (int j = 0; j < 4; ++j) { \
            int d = vdb + j; \
            *(uint32_t*)&Vtlds[((T) & 1) ^ 1][(d * KBLK + vkp) ^ ((d & 7) << 3)] = \
                f16b(va[j]) | (f16b(vb[j]) << 16); \
        } \
    } \
} while (0)

// group-end store: 8 iterations, each 1 KB as two contiguous 512B row-segments
#define STORE_GROUP(TE) do { \
    const int ttp = ((TE) + phase) & 31; \
    _Pragma("unroll") \
    for (int i = 0; i < 8; ++i) { \
        int row = 2 * i + (lane >> 5); \
        int cf  = 4 * (lane & 31); \
        int idx = (row * 128 + cf) ^ ((row & 7) << 3); \
        f16x4 a = *(const f16x4*)&Astage[wq][idx]; \
        float4v o; o[0]=(float)a[0]; o[1]=(float)a[1]; o[2]=(float)a[2]; o[3]=(float)a[3]; \
        __builtin_nontemporal_store(o, (float4v*)(AttnOut + mat_base + \
            (size_t)(qw0 + row) * S_LEN + ttp * KBLK + cf)); \
    } \
} while (0)

#define S2E(T) do { \
    BARRIER(); \
    S2_LOADS(T); \
    if ((T) + 2 < KSTEPS) buNxt = *BITSADDR(((T) >> 1) + 1); \
    S2_CORE(T, buCur & 0xffffu, 0); \
    S2_STAGE(T); \
} while (0)

#define S2O(T) do { \
    BARRIER(); \
    S2_LOADS(T); \
    S2_CORE(T, buCur >> 16, 1); \
    S2_STAGE(T); \
    STORE_GROUP((T) - 1); \
    buCur = buNxt; \
} while (0)

    S2E(0);  S2O(1);  S2E(2);  S2O(3);  S2E(4);  S2O(5);  S2E(6);  S2O(7);
    S2E(8);  S2O(9);  S2E(10); S2O(11); S2E(12); S2O(13); S2E(14); S2O(15);
    S2E(16); S2O(17); S2E(18); S2O(19); S2E(20); S2O(21); S2E(22); S2O(23);
    S2E(24); S2O(25); S2E(26); S2O(27); S2E(28); S2O(29); S2E(30); S2O(31);

    // epilogue: prob (already normalized; C/D layout col=lr, row=4g+r)
    #pragma unroll
    for (int dt = 0; dt < 4; ++dt) {
        #pragma unroll
        for (int r = 0; r < 4; ++r) {
            int qrow = qw0 + 4 * g + r;
            ProbOut[qkv_base + (size_t)qrow * D_DIM + 16 * dt + lr] = acc[dt][r];
        }
    }
}

extern "C" void kernel_launch(void* const* d_in, const int* in_sizes, int n_in,
                              void* d_out, int out_size, void* d_ws, size_t ws_size,
                              hipStream_t stream)
{
    const float* Q = (const float*)d_in[0];
    const float* K = (const float*)d_in[1];
    const float* V = (const float*)d_in[2];
    const int*   M = (const int*)d_in[3];

    float* prob = (float*)d_out;                          // [4,16,2048,64]
    float* attn = prob + (size_t)4 * 16 * 2048 * 64;      // [4,16,2048,2048]

    dim3 grid(64 * (S_LEN / QBLK));   // 1024
    dim3 block(NTHREADS);
    sdpa_kernel<<<grid, block, 0, stream>>>(Q, K, V, M, prob, attn);
}

// Round 9
// 493.627 us; speedup vs baseline: 2.5958x; 1.2915x over previous
//
#include <hip/hip_runtime.h>
#include <stdint.h>

typedef _Float16 f16;
typedef _Float16 f16x8 __attribute__((ext_vector_type(8)));
typedef _Float16 f16x4 __attribute__((ext_vector_type(4)));
typedef float f32x4 __attribute__((ext_vector_type(4)));
typedef int int4v __attribute__((ext_vector_type(4)));
typedef float float4v __attribute__((ext_vector_type(4)));

#define S_LEN 2048
#define D_DIM 64
#define QBLK 128
#define KBLK 64
#define NTHREADS 512
#define KSTEPS 32

// LDS-visibility barrier: no vmcnt drain (T4) — global loads/stores stay in flight.
#define BARRIER() do { \
    asm volatile("s_waitcnt lgkmcnt(0)" ::: "memory"); \
    __builtin_amdgcn_s_barrier(); \
    asm volatile("" ::: "memory"); \
} while (0)

__device__ __forceinline__ f16x8 cvt8(float4v a, float4v b) {
    f16x8 f;
    f[0]=(f16)a[0]; f[1]=(f16)a[1]; f[2]=(f16)a[2]; f[3]=(f16)a[3];
    f[4]=(f16)b[0]; f[5]=(f16)b[1]; f[6]=(f16)b[2]; f[7]=(f16)b[3];
    return f;
}
__device__ __forceinline__ uint32_t f16b(float x) {
    union { f16 h; uint16_t u; } c; c.h = (f16)x; return c.u;
}

// QK^T from swizzled Klds[CUR]: c[ct][r] = S[q=qw0+lr][k = tile*64 + 16ct + 4g + r]
#define QKT_LDS(C, CUR) do { \
    _Pragma("unroll") \
    for (int ct = 0; ct < 4; ++ct) { \
        C[ct] = (f32x4){0.f, 0.f, 0.f, 0.f}; \
        _Pragma("unroll") \
        for (int h = 0; h < 2; ++h) { \
            int rowl = 16 * ct + lr; \
            int idx = (rowl * D_DIM + 8 * g + 32 * h) ^ ((rowl & 7) << 3); \
            f16x8 kf = *(const f16x8*)(&Klds[CUR][idx]); \
            C[ct] = __builtin_amdgcn_mfma_f32_16x16x32_f16(kf, qfrag[h], C[ct], 0, 0, 0); \
        } \
    } \
} while (0)

// mask loads for kstep TT: 4 instrs, each = 4 rows x 256B contiguous runs
#define MLOAD(TT) do { \
    const int* mp = Mg + mat_base + (size_t)(qw0 + mrl) * S_LEN + (TT) * KBLK + mcl; \
    mq0 = __builtin_nontemporal_load((const int4v*)(mp)); \
    mq1 = __builtin_nontemporal_load((const int4v*)(mp + 4 * S_LEN)); \
    mq2 = __builtin_nontemporal_load((const int4v*)(mp + 8 * S_LEN)); \
    mq3 = __builtin_nontemporal_load((const int4v*)(mp + 12 * S_LEN)); \
} while (0)

// pack + shfl-redistribute: bits[4ct+r] = mask(row lr, col 16ct+4g+r)
#define MBITS(BITS) do { \
    uint32_t nib4 = 0; \
    _Pragma("unroll") \
    for (int r = 0; r < 4; ++r) { \
        nib4 |= (mq0[r] != 0 ? 1u : 0u) << r; \
        nib4 |= (mq1[r] != 0 ? 1u : 0u) << (4 + r); \
        nib4 |= (mq2[r] != 0 ? 1u : 0u) << (8 + r); \
        nib4 |= (mq3[r] != 0 ? 1u : 0u) << (12 + r); \
    } \
    const int nsh = 4 * (lr >> 2); \
    BITS = 0; \
    _Pragma("unroll") \
    for (int ct = 0; ct < 4; ++ct) { \
        uint32_t v = (uint32_t)__shfl((int)nib4, 16 * (lr & 3) + 4 * ct + g, 64); \
        BITS |= ((v >> nsh) & 15u) << (4 * ct); \
    } \
} while (0)

__global__ __launch_bounds__(NTHREADS, 4)
void sdpa_kernel(const float* __restrict__ Qg, const float* __restrict__ Kg,
                 const float* __restrict__ Vg, const int* __restrict__ Mg,
                 float* __restrict__ ProbOut, float* __restrict__ AttnOut)
{
    // LDS: 16 (K dbuf) + 16 (Vt dbuf) + 16 (Astage) = 48 KB
    __shared__ f16 Klds[2][KBLK * D_DIM];    // [k][d], rows XOR-swizzled
    __shared__ f16 Vtlds[2][D_DIM * KBLK];   // [d][k'], k'-permuted, rows XOR-swizzled
    __shared__ f16 Astage[8][16 * 64];       // per-wave attn tile [q16][col64], swizzled

    const int tid  = threadIdx.x;
    const int lane = tid & 63;
    const int wq   = tid >> 6;
    const int g    = lane >> 4;
    const int lr   = lane & 15;

    const int wid = ((blockIdx.x & 7) << 7) + (blockIdx.x >> 3);   // XCD swizzle
    const int bh  = wid >> 4;
    const int qb  = wid & 15;
    const int phase = ((bh & 3) << 3) | ((qb & 1) << 2);           // R5's stagger

    const size_t qkv_base = (size_t)bh * S_LEN * D_DIM;
    const size_t mat_base = (size_t)bh * S_LEN * S_LEN;
    const int qw0 = qb * QBLK + wq * 16;

    // mask/store lane mapping (256B-run pattern)
    const int mrl = lane >> 4;        // row sub 0..3 (instr adds 4i)
    const int mcl = 4 * (lane & 15);  // col 0..60

    f16x8 qfrag[2];
    {
        const float* qp = Qg + qkv_base + (size_t)(qw0 + lr) * D_DIM + g * 8;
        #pragma unroll
        for (int h = 0; h < 2; ++h)
            qfrag[h] = cvt8(*(const float4v*)(qp + 32 * h),
                            *(const float4v*)(qp + 32 * h + 4));
    }

    const int srow = tid >> 3, scol = (tid & 7) * 8;
    const int sidx = (srow * D_DIM + scol) ^ ((srow & 7) << 3);
    const int vrp  = tid >> 4, vdb = (tid & 15) * 4;
    const int vk   = 2 * vrp;
    const int vkp  = (vk & 3) | (((vk >> 4) & 3) << 2) | (((vk >> 2) & 3) << 4);

    const float* kbase = Kg + qkv_base;
    const float* vbase = Vg + qkv_base;

    uint32_t mbits[16];
    #pragma unroll
    for (int i = 0; i < 16; ++i) mbits[i] = 0u;

    // ============ sweep 1: l = sum(exp(s)); bits -> registers ============
    float lacc[4] = {0.f, 0.f, 0.f, 0.f};
    float4v ka, kb;
    int4v mq0, mq1, mq2, mq3;

    {   // prologue
        const float* kp = kbase + (size_t)(phase * KBLK + srow) * D_DIM + scol;
        ka = *(const float4v*)kp; kb = *(const float4v*)(kp + 4);
        MLOAD(phase);
        *(f16x8*)&Klds[0][sidx] = cvt8(ka, kb);
    }

#define S1B(T) do { \
    BARRIER(); \
    uint32_t bits; \
    MBITS(bits); \
    mbits[(T) >> 1] |= bits << (16 * ((T) & 1)); \
    if ((T) + 1 < KSTEPS) { \
        const int tn = ((T) + 1 + phase) & 31; \
        const float* kp = kbase + (size_t)(tn * KBLK + srow) * D_DIM + scol; \
        ka = *(const float4v*)kp; kb = *(const float4v*)(kp + 4); \
        MLOAD(tn); \
    } \
    f32x4 c[4]; \
    QKT_LDS(c, (T) & 1); \
    _Pragma("unroll") \
    for (int ct = 0; ct < 4; ++ct) { \
        _Pragma("unroll") \
        for (int r = 0; r < 4; ++r) { \
            float s = c[ct][r] * 0.125f; \
            float p = ((bits >> (4 * ct + r)) & 1) ? 0.f : __expf(s); /* |s|<=8 */ \
            lacc[r] += p; \
        } \
    } \
    if ((T) + 1 < KSTEPS) *(f16x8*)&Klds[((T) & 1) ^ 1][sidx] = cvt8(ka, kb); \
} while (0)

    S1B(0);  S1B(1);  S1B(2);  S1B(3);  S1B(4);  S1B(5);  S1B(6);  S1B(7);
    S1B(8);  S1B(9);  S1B(10); S1B(11); S1B(12); S1B(13); S1B(14); S1B(15);
    S1B(16); S1B(17); S1B(18); S1B(19); S1B(20); S1B(21); S1B(22); S1B(23);
    S1B(24); S1B(25); S1B(26); S1B(27); S1B(28); S1B(29); S1B(30); S1B(31);

    float lsum = (lacc[0] + lacc[1]) + (lacc[2] + lacc[3]);
    lsum += __shfl_xor(lsum, 16, 64);
    lsum += __shfl_xor(lsum, 32, 64);
    const float inv_l = 1.f / lsum;

    // ============ sweep 2: recompute s, stage+store attn (256B runs), PV ============
    f32x4 acc[4];
    #pragma unroll
    for (int dt = 0; dt < 4; ++dt) acc[dt] = (f32x4){0.f, 0.f, 0.f, 0.f};

    float4v va, vb;
    {   // prologue (t=31 of sweep 1 read buf1; buf0 write is safe)
        const float* kp = kbase + (size_t)(phase * KBLK + srow) * D_DIM + scol;
        ka = *(const float4v*)kp; kb = *(const float4v*)(kp + 4);
        const float* vp = vbase + (size_t)(phase * KBLK + vk) * D_DIM + vdb;
        va = *(const float4v*)vp; vb = *(const float4v*)(vp + D_DIM);
        *(f16x8*)&Klds[0][sidx] = cvt8(ka, kb);
        #pragma unroll
        for (int j = 0; j < 4; ++j) {
            int d = vdb + j;
            *(uint32_t*)&Vtlds[0][(d * KBLK + vkp) ^ ((d & 7) << 3)] =
                f16b(va[j]) | (f16b(vb[j]) << 16);
        }
    }

#define S2B(T) do { \
    const int tt = ((T) + phase) & 31; \
    BARRIER(); \
    if ((T) + 1 < KSTEPS) { \
        const int tn = ((T) + 1 + phase) & 31; \
        const float* kp = kbase + (size_t)(tn * KBLK + srow) * D_DIM + scol; \
        ka = *(const float4v*)kp; kb = *(const float4v*)(kp + 4); \
        const float* vp = vbase + (size_t)(tn * KBLK + vk) * D_DIM + vdb; \
        va = *(const float4v*)vp; vb = *(const float4v*)(vp + D_DIM); \
    } \
    f32x4 c[4]; \
    QKT_LDS(c, (T) & 1); \
    const uint32_t bits = (mbits[(T) >> 1] >> (16 * ((T) & 1))) & 0xffffu; \
    f16x4 pa[4]; \
    _Pragma("unroll") \
    for (int ct = 0; ct < 4; ++ct) { \
        _Pragma("unroll") \
        for (int r = 0; r < 4; ++r) { \
            float s = c[ct][r] * 0.125f; \
            float p = ((bits >> (4 * ct + r)) & 1) ? 0.f : __expf(s); \
            pa[ct][r] = (f16)(p * inv_l); \
        } \
        *(f16x4*)&Astage[wq][(lr * 64 + 16 * ct + 4 * g) ^ ((lr & 7) << 3)] = pa[ct]; \
    } \
    _Pragma("unroll") \
    for (int dt = 0; dt < 4; ++dt) { \
        int row = 16 * dt + lr; \
        f16x8 vfA = *(const f16x8*)&Vtlds[(T) & 1][(row * KBLK + 16 * g)     ^ ((lr & 7) << 3)]; \
        f16x8 vfB = *(const f16x8*)&Vtlds[(T) & 1][(row * KBLK + 16 * g + 8) ^ ((lr & 7) << 3)]; \
        acc[dt] = __builtin_amdgcn_mfma_f32_16x16x16f16( \
            pa[0], __builtin_shufflevector(vfA, vfA, 0, 1, 2, 3), acc[dt], 0, 0, 0); \
        acc[dt] = __builtin_amdgcn_mfma_f32_16x16x16f16( \
            pa[1], __builtin_shufflevector(vfA, vfA, 4, 5, 6, 7), acc[dt], 0, 0, 0); \
        acc[dt] = __builtin_amdgcn_mfma_f32_16x16x16f16( \
            pa[2], __builtin_shufflevector(vfB, vfB, 0, 1, 2, 3), acc[dt], 0, 0, 0); \
        acc[dt] = __builtin_amdgcn_mfma_f32_16x16x16f16( \
            pa[3], __builtin_shufflevector(vfB, vfB, 4, 5, 6, 7), acc[dt], 0, 0, 0); \
    } \
    _Pragma("unroll") \
    for (int i = 0; i < 4; ++i) {   /* flush: 4 instrs x (4 rows x 256B runs) */ \
        int R = 4 * i + mrl; \
        f16x4 a = *(const f16x4*)&Astage[wq][(R * 64 + mcl) ^ ((R & 7) << 3)]; \
        float4v o; o[0]=(float)a[0]; o[1]=(float)a[1]; o[2]=(float)a[2]; o[3]=(float)a[3]; \
        __builtin_nontemporal_store(o, (float4v*)(AttnOut + mat_base + \
            (size_t)(qw0 + R) * S_LEN + tt * KBLK + mcl)); \
    } \
    if ((T) + 1 < KSTEPS) { \
        *(f16x8*)&Klds[((T) & 1) ^ 1][sidx] = cvt8(ka, kb); \
        _Pragma("unroll") \
        for (int j = 0; j < 4; ++j) { \
            int d = vdb + j; \
            *(uint32_t*)&Vtlds[((T) & 1) ^ 1][(d * KBLK + vkp) ^ ((d & 7) << 3)] = \
                f16b(va[j]) | (f16b(vb[j]) << 16); \
        } \
    } \
} while (0)

    S2B(0);  S2B(1);  S2B(2);  S2B(3);  S2B(4);  S2B(5);  S2B(6);  S2B(7);
    S2B(8);  S2B(9);  S2B(10); S2B(11); S2B(12); S2B(13); S2B(14); S2B(15);
    S2B(16); S2B(17); S2B(18); S2B(19); S2B(20); S2B(21); S2B(22); S2B(23);
    S2B(24); S2B(25); S2B(26); S2B(27); S2B(28); S2B(29); S2B(30); S2B(31);

    // epilogue: prob (already normalized; C/D layout col=lr, row=4g+r)
    #pragma unroll
    for (int dt = 0; dt < 4; ++dt) {
        #pragma unroll
        for (int r = 0; r < 4; ++r) {
            int qrow = qw0 + 4 * g + r;
            ProbOut[qkv_base + (size_t)qrow * D_DIM + 16 * dt + lr] = acc[dt][r];
        }
    }
}

extern "C" void kernel_launch(void* const* d_in, const int* in_sizes, int n_in,
                              void* d_out, int out_size, void* d_ws, size_t ws_size,
                              hipStream_t stream)
{
    const float* Q = (const float*)d_in[0];
    const float* K = (const float*)d_in[1];
    const float* V = (const float*)d_in[2];
    const int*   M = (const int*)d_in[3];

    float* prob = (float*)d_out;                          // [4,16,2048,64]
    float* attn = prob + (size_t)4 * 16 * 2048 * 64;      // [4,16,2048,2048]

    dim3 grid(64 * (S_LEN / QBLK));   // 1024
    dim3 block(NTHREADS);
    sdpa_kernel<<<grid, block, 0, stream>>>(Q, K, V, M, prob, attn);
}